// Round 1
// baseline (520.533 us; speedup 1.0000x reference)
//
#include <hip/hip_runtime.h>
#include <stdint.h>
#include <math.h>

#define NTOK 8192
#define DIM  512
#define FDIM 2048
#define NEXP 8
#define RMAX 17408   // 136 * 128 >= 2*NTOK + NEXP*127 alignment pad
#define NMT  136

typedef __attribute__((ext_vector_type(8))) __bf16 bf16x8;
typedef __attribute__((ext_vector_type(4))) float  f32x4;

// ---------------- workspace layout (bytes) ----------------
#define OFF_W1T    ((size_t)0)
#define SZ_W1T     ((size_t)NEXP * DIM * FDIM * 2)   // 16 MiB
#define OFF_W2T    (OFF_W1T + SZ_W1T)
#define SZ_W2T     SZ_W1T
#define OFF_H      (OFF_W2T + SZ_W2T)
#define SZ_H       ((size_t)RMAX * FDIM * 2)         // 68 MiB
#define OFF_META   (OFF_H + SZ_H)                    // counts[8] @0, offsets[9] @8, mtile_e[136] @32 (ints)
#define SZ_META    ((size_t)1024)
#define OFF_TOKROW (OFF_META + SZ_META)
#define SZ_TOKROW  ((size_t)RMAX * 4)
#define OFF_GATEROW (OFF_TOKROW + SZ_TOKROW)
#define SZ_GATEROW ((size_t)RMAX * 4)
#define OFF_XG     (OFF_GATEROW + SZ_GATEROW)
#define SZ_XG      ((size_t)RMAX * DIM * 2)
#define OFF_TOKE   (OFF_XG + SZ_XG)
#define OFF_TOKSLOT (OFF_TOKE + (size_t)NTOK * 8)
#define OFF_TOKG   (OFF_TOKSLOT + (size_t)NTOK * 8)
#define ZERO_START OFF_META
#define ZERO_LEN   (OFF_XG + SZ_XG - OFF_META)

__device__ __forceinline__ unsigned short f2bf(float f) {
  union { float f; unsigned int u; } v; v.f = f;
  unsigned int u = v.u;
  return (unsigned short)((u + 0x7fffu + ((u >> 16) & 1u)) >> 16);
}

// ---------------- transpose + bf16 cast: src [B][R][C] f32 -> dst [B][C][R] bf16 ----------------
__global__ void transpose_cast(const float* __restrict__ src, unsigned short* __restrict__ dst,
                               int R, int C) {
  __shared__ float t[32][33];
  const int b = blockIdx.z;
  const int r0 = blockIdx.y * 32, c0 = blockIdx.x * 32;
  const float* s = src + (size_t)b * R * C;
  unsigned short* d = dst + (size_t)b * R * C;
  const int tr = threadIdx.x >> 5, tc = threadIdx.x & 31;  // tr 0..7
  #pragma unroll
  for (int i = 0; i < 4; i++)
    t[tr + i * 8][tc] = s[(size_t)(r0 + tr + i * 8) * C + (c0 + tc)];
  __syncthreads();
  #pragma unroll
  for (int i = 0; i < 4; i++)
    d[(size_t)(c0 + tr + i * 8) * R + (r0 + tc)] = f2bf(t[tc][tr + i * 8]);
}

// ---------------- gating: fp64 logits, top-2, softmax, per-expert slot assignment ----------------
__global__ void gate_kernel(const float* __restrict__ x, const float* __restrict__ Wg,
                            int* __restrict__ counts, int2* __restrict__ tok_e,
                            int2* __restrict__ tok_slot, float2* __restrict__ tok_g) {
  const int wid = threadIdx.x >> 6;
  const int lane = threadIdx.x & 63;
  const int n = blockIdx.x * 4 + wid;
  double acc[NEXP];
  #pragma unroll
  for (int e = 0; e < NEXP; e++) acc[e] = 0.0;
  #pragma unroll
  for (int i = 0; i < 8; i++) {
    int dd = lane + i * 64;
    double xv = (double)x[(size_t)n * DIM + dd];
    const float* wr = Wg + (size_t)dd * NEXP;
    #pragma unroll
    for (int e = 0; e < NEXP; e++) acc[e] += xv * (double)wr[e];
  }
  #pragma unroll
  for (int s = 32; s > 0; s >>= 1)
    #pragma unroll
    for (int e = 0; e < NEXP; e++) acc[e] += __shfl_xor(acc[e], s, 64);
  if (lane == 0) {
    int i0 = 0;
    #pragma unroll
    for (int e = 1; e < NEXP; e++) if (acc[e] > acc[i0]) i0 = e;
    int i1 = (i0 == 0) ? 1 : 0;
    #pragma unroll
    for (int e = 0; e < NEXP; e++) { if (e == i0 || e == i1) continue; if (acc[e] > acc[i1]) i1 = e; }
    double v0 = acc[i0], v1 = acc[i1];
    double e1 = exp(v1 - v0), ssum = 1.0 + e1;
    float g0 = (float)(1.0 / ssum), g1 = (float)(e1 / ssum);
    int s0 = atomicAdd(&counts[i0], 1);
    int s1 = atomicAdd(&counts[i1], 1);
    tok_e[n] = make_int2(i0, i1);
    tok_slot[n] = make_int2(s0, s1);
    tok_g[n] = make_float2(g0, g1);
  }
}

// ---------------- 128-aligned segment offsets + per-M-tile expert id ----------------
__global__ void offsets_kernel(const int* __restrict__ counts, int* __restrict__ offsets,
                               int* __restrict__ mtile_e) {
  if (threadIdx.x == 0 && blockIdx.x == 0) {
    int off = 0;
    for (int e = 0; e < NEXP; e++) { offsets[e] = off; off += (counts[e] + 127) & ~127; }
    offsets[NEXP] = off;
    for (int t = 0; t < NMT; t++) {
      int r = t * 128, e = NEXP - 1;
      for (int q = 0; q < NEXP; q++)
        if (r >= offsets[q] && r < offsets[q + 1]) { e = q; break; }
      mtile_e[t] = e;
    }
  }
}

// ---------------- gather routed token rows into contiguous bf16 segments ----------------
__global__ void gather_kernel(const float* __restrict__ x, const int2* __restrict__ tok_e,
                              const int2* __restrict__ tok_slot, const float2* __restrict__ tok_g,
                              const int* __restrict__ offsets, int* __restrict__ tokrow,
                              float* __restrict__ gaterow, ushort4* __restrict__ xg) {
  const int p = blockIdx.x, n = p >> 1, k = p & 1;
  int2 te = tok_e[n]; int2 ts = tok_slot[n]; float2 tg = tok_g[n];
  const int e = k ? te.y : te.x;
  const int slot = k ? ts.y : ts.x;
  const float g = k ? tg.y : tg.x;
  const int r = offsets[e] + slot;
  if (threadIdx.x == 0) { tokrow[r] = n; gaterow[r] = g; }
  const float4* xr = (const float4*)(x + (size_t)n * DIM);
  float4 v = xr[threadIdx.x];
  ushort4 o;
  o.x = f2bf(v.x); o.y = f2bf(v.y); o.z = f2bf(v.z); o.w = f2bf(v.w);
  xg[(size_t)r * (DIM / 4) + threadIdx.x] = o;
}

// ---------------- shared 128x128xBK32 bf16 MFMA GEMM core (A row-major, B^T row-major) ----------------
template <int K, int LDA, int LDB>
__device__ __forceinline__ void gemm_core(const unsigned short* __restrict__ A,
                                          const unsigned short* __restrict__ B,
                                          int m0, int n0, f32x4 acc[4][4]) {
  __shared__ __align__(16) unsigned short As[128 * 32];
  __shared__ __align__(16) unsigned short Bs[128 * 32];
  const int tid = threadIdx.x;
  const int wid = tid >> 6, lane = tid & 63;
  const int wm = (wid >> 1) * 64, wn = (wid & 1) * 64;
  const int quad = lane >> 4, l16 = lane & 15;
  const int srow = tid >> 2;          // 0..63
  const int scol = (tid & 3) << 3;    // 0,8,16,24 (elements)
  const unsigned short* Ar0 = A + (size_t)(m0 + srow) * LDA + scol;
  const unsigned short* Ar1 = A + (size_t)(m0 + srow + 64) * LDA + scol;
  const unsigned short* Br0 = B + (size_t)(n0 + srow) * LDB + scol;
  const unsigned short* Br1 = B + (size_t)(n0 + srow + 64) * LDB + scol;
  #pragma unroll 1
  for (int kt = 0; kt < K; kt += 32) {
    uint4 a0 = *(const uint4*)(Ar0 + kt);
    uint4 a1 = *(const uint4*)(Ar1 + kt);
    uint4 b0 = *(const uint4*)(Br0 + kt);
    uint4 b1 = *(const uint4*)(Br1 + kt);
    __syncthreads();
    *(uint4*)(As + srow * 32 + scol) = a0;
    *(uint4*)(As + (srow + 64) * 32 + scol) = a1;
    *(uint4*)(Bs + srow * 32 + scol) = b0;
    *(uint4*)(Bs + (srow + 64) * 32 + scol) = b1;
    __syncthreads();
    bf16x8 af[4], bfr[4];
    #pragma unroll
    for (int i = 0; i < 4; i++) {
      af[i]  = *(const bf16x8*)(As + (wm + i * 16 + l16) * 32 + quad * 8);
      bfr[i] = *(const bf16x8*)(Bs + (wn + i * 16 + l16) * 32 + quad * 8);
    }
    #pragma unroll
    for (int mi = 0; mi < 4; mi++)
      #pragma unroll
      for (int ni = 0; ni < 4; ni++)
        acc[mi][ni] = __builtin_amdgcn_mfma_f32_16x16x32_bf16(af[mi], bfr[ni], acc[mi][ni], 0, 0, 0);
  }
}

// ---------------- GEMM1: h = relu(xg @ W1[e] + b1[e]) -> bf16 ----------------
__global__ __launch_bounds__(256) void gemm1_kernel(const unsigned short* __restrict__ xg,
    const unsigned short* __restrict__ W1t, const int* __restrict__ mtile_e,
    const float* __restrict__ b1, unsigned short* __restrict__ h) {
  const int bm = blockIdx.x, bn = blockIdx.y;
  const int e = mtile_e[bm];
  f32x4 acc[4][4];
  #pragma unroll
  for (int i = 0; i < 4; i++)
    #pragma unroll
    for (int j = 0; j < 4; j++) acc[i][j] = (f32x4){0.f, 0.f, 0.f, 0.f};
  gemm_core<DIM, DIM, DIM>(xg, W1t + (size_t)e * FDIM * DIM, bm * 128, bn * 128, acc);
  const int tid = threadIdx.x, wid = tid >> 6, lane = tid & 63;
  const int wm = (wid >> 1) * 64, wn = (wid & 1) * 64, quad = lane >> 4, l16 = lane & 15;
  #pragma unroll
  for (int mi = 0; mi < 4; mi++) {
    #pragma unroll
    for (int ni = 0; ni < 4; ni++) {
      const int col = bn * 128 + wn + ni * 16 + l16;
      const float bb = b1[e * FDIM + col];
      #pragma unroll
      for (int r = 0; r < 4; r++) {
        const int row = bm * 128 + wm + mi * 16 + quad * 4 + r;
        float v = acc[mi][ni][r] + bb;
        h[(size_t)row * FDIM + col] = f2bf(v > 0.f ? v : 0.f);
      }
    }
  }
}

// ---------------- GEMM2: o = h @ W2[e] + b2[e]; scatter gate*exp(o) ----------------
__global__ __launch_bounds__(256) void gemm2_kernel(const unsigned short* __restrict__ h,
    const unsigned short* __restrict__ W2t, const int* __restrict__ mtile_e,
    const int* __restrict__ tokrow, const float* __restrict__ gaterow,
    const float* __restrict__ b2, float* __restrict__ out) {
  const int bm = blockIdx.x, bn = blockIdx.y;
  const int e = mtile_e[bm];
  f32x4 acc[4][4];
  #pragma unroll
  for (int i = 0; i < 4; i++)
    #pragma unroll
    for (int j = 0; j < 4; j++) acc[i][j] = (f32x4){0.f, 0.f, 0.f, 0.f};
  gemm_core<FDIM, FDIM, FDIM>(h, W2t + (size_t)e * DIM * FDIM, bm * 128, bn * 128, acc);
  const int tid = threadIdx.x, wid = tid >> 6, lane = tid & 63;
  const int wm = (wid >> 1) * 64, wn = (wid & 1) * 64, quad = lane >> 4, l16 = lane & 15;
  #pragma unroll
  for (int mi = 0; mi < 4; mi++) {
    #pragma unroll
    for (int r = 0; r < 4; r++) {
      const int row = bm * 128 + wm + mi * 16 + quad * 4 + r;
      const float g = gaterow[row];
      if (g != 0.f) {
        const int tok = tokrow[row];
        #pragma unroll
        for (int ni = 0; ni < 4; ni++) {
          const int col = bn * 128 + wn + ni * 16 + l16;
          const float o = acc[mi][ni][r] + b2[e * DIM + col];
          atomicAdd(&out[(size_t)tok * DIM + col], g * expf(o));
        }
      }
    }
  }
}

// ---------------- finalize: log with eps floor, in place ----------------
__global__ void log_kernel(float* __restrict__ out) {
  const int i = blockIdx.x * 256 + threadIdx.x;
  float v = out[i];
  v = (v == 0.0f) ? 2.220446049250313e-16f : v;
  out[i] = logf(v);
}

extern "C" void kernel_launch(void* const* d_in, const int* in_sizes, int n_in,
                              void* d_out, int out_size, void* d_ws, size_t ws_size,
                              hipStream_t stream) {
  const float* x  = (const float*)d_in[0];
  const float* Wg = (const float*)d_in[1];
  const float* W1 = (const float*)d_in[2];
  const float* b1 = (const float*)d_in[3];
  const float* W2 = (const float*)d_in[4];
  const float* b2 = (const float*)d_in[5];
  float* out = (float*)d_out;
  char* ws = (char*)d_ws;

  unsigned short* W1t = (unsigned short*)(ws + OFF_W1T);
  unsigned short* W2t = (unsigned short*)(ws + OFF_W2T);
  unsigned short* h   = (unsigned short*)(ws + OFF_H);
  int* meta    = (int*)(ws + OFF_META);
  int* counts  = meta;
  int* offsets = meta + 8;
  int* mtile_e = meta + 32;
  int* tokrow     = (int*)(ws + OFF_TOKROW);
  float* gaterow  = (float*)(ws + OFF_GATEROW);
  unsigned short* xg = (unsigned short*)(ws + OFF_XG);
  int2* tok_e    = (int2*)(ws + OFF_TOKE);
  int2* tok_slot = (int2*)(ws + OFF_TOKSLOT);
  float2* tok_g  = (float2*)(ws + OFF_TOKG);

  hipMemsetAsync(d_out, 0, (size_t)NTOK * DIM * 4, stream);
  hipMemsetAsync(ws + ZERO_START, 0, ZERO_LEN, stream);

  transpose_cast<<<dim3(FDIM / 32, DIM / 32, NEXP), 256, 0, stream>>>(W1, W1t, DIM, FDIM);
  transpose_cast<<<dim3(DIM / 32, FDIM / 32, NEXP), 256, 0, stream>>>(W2, W2t, FDIM, DIM);
  gate_kernel<<<NTOK / 4, 256, 0, stream>>>(x, Wg, counts, tok_e, tok_slot, tok_g);
  offsets_kernel<<<1, 64, 0, stream>>>(counts, offsets, mtile_e);
  gather_kernel<<<NTOK * 2, 128, 0, stream>>>(x, tok_e, tok_slot, tok_g, offsets,
                                              tokrow, gaterow, (ushort4*)xg);
  gemm1_kernel<<<dim3(NMT, FDIM / 128), 256, 0, stream>>>(xg, W1t, mtile_e, b1, h);
  gemm2_kernel<<<dim3(NMT, DIM / 128), 256, 0, stream>>>(h, W2t, mtile_e, tokrow, gaterow, b2, out);
  log_kernel<<<NTOK * DIM / 256, 256, 0, stream>>>(out);
}

// Round 3
// 367.384 us; speedup vs baseline: 1.4169x; 1.4169x over previous
//
#include <hip/hip_runtime.h>
#include <stdint.h>
#include <math.h>

#define NTOK 8192
#define DIM  512
#define FDIM 2048
#define NEXP 8
#define RMAX 17408   // 136 * 128 >= 2*NTOK + NEXP*127 alignment pad
#define NMT  136

typedef __attribute__((ext_vector_type(8))) __bf16 bf16x8;
typedef __attribute__((ext_vector_type(4))) float  f32x4;

// ---------------- workspace layout (bytes) ----------------
#define OFF_W1T    ((size_t)0)
#define SZ_W1T     ((size_t)NEXP * DIM * FDIM * 2)   // 16 MiB
#define OFF_W2T    (OFF_W1T + SZ_W1T)
#define SZ_W2T     SZ_W1T
#define OFF_H      (OFF_W2T + SZ_W2T)
#define SZ_H       ((size_t)RMAX * FDIM * 2)         // 68 MiB
#define OFF_META   (OFF_H + SZ_H)                    // counts[8] @0, offsets[9] @8, mtile_e[136] @32 (ints)
#define SZ_META    ((size_t)1024)
#define OFF_TOKROW (OFF_META + SZ_META)
#define SZ_TOKROW  ((size_t)RMAX * 4)
#define OFF_GATEROW (OFF_TOKROW + SZ_TOKROW)
#define SZ_GATEROW ((size_t)RMAX * 4)
#define OFF_XG     (OFF_GATEROW + SZ_GATEROW)
#define SZ_XG      ((size_t)RMAX * DIM * 2)
#define OFF_TOKE   (OFF_XG + SZ_XG)
#define OFF_TOKSLOT (OFF_TOKE + (size_t)NTOK * 8)
#define OFF_TOKG   (OFF_TOKSLOT + (size_t)NTOK * 8)
#define ZERO_START OFF_META
#define ZERO_LEN   (OFF_XG + SZ_XG - OFF_META)

__device__ __forceinline__ unsigned short f2bf(float f) {
  union { float f; unsigned int u; } v; v.f = f;
  unsigned int u = v.u;
  return (unsigned short)((u + 0x7fffu + ((u >> 16) & 1u)) >> 16);
}

// async 16B/lane global->LDS; lds base must be wave-uniform, HW adds lane*16
__device__ __forceinline__ void gld16(const unsigned short* g, unsigned short* l) {
  __builtin_amdgcn_global_load_lds(
      (const __attribute__((address_space(1))) void*)g,
      (__attribute__((address_space(3))) void*)l, 16, 0, 0);
}

// ---------------- transpose + bf16 cast: src [B][R][C] f32 -> dst [B][C][R] bf16 ----------------
__global__ void transpose_cast(const float* __restrict__ src, unsigned short* __restrict__ dst,
                               int R, int C) {
  __shared__ float t[32][33];
  const int b = blockIdx.z;
  const int r0 = blockIdx.y * 32, c0 = blockIdx.x * 32;
  const float* s = src + (size_t)b * R * C;
  unsigned short* d = dst + (size_t)b * R * C;
  const int tr = threadIdx.x >> 5, tc = threadIdx.x & 31;  // tr 0..7
  #pragma unroll
  for (int i = 0; i < 4; i++)
    t[tr + i * 8][tc] = s[(size_t)(r0 + tr + i * 8) * C + (c0 + tc)];
  __syncthreads();
  #pragma unroll
  for (int i = 0; i < 4; i++)
    d[(size_t)(c0 + tr + i * 8) * R + (r0 + tc)] = f2bf(t[tc][tr + i * 8]);
}

// ---------------- gating: fp64 logits, top-2, softmax; hierarchical slot counting ----------------
// 128 blocks x 64 tokens: LDS histogram for local slots, 8 global atomics/block.
#define GB 128
#define TPB 64   // tokens per block (4 waves x 16)
__global__ __launch_bounds__(256) void gate_kernel(const float* __restrict__ x,
                            const float* __restrict__ Wg,
                            int* __restrict__ counts, int2* __restrict__ tok_e,
                            int2* __restrict__ tok_slot, float2* __restrict__ tok_g) {
  __shared__ int hist[NEXP];
  __shared__ int base[NEXP];
  __shared__ int le[TPB][2];
  __shared__ int ls[TPB][2];
  __shared__ float lg[TPB][2];
  const int wid = threadIdx.x >> 6;
  const int lane = threadIdx.x & 63;
  if (threadIdx.x < NEXP) hist[threadIdx.x] = 0;
  __syncthreads();
  for (int t = 0; t < 16; t++) {
    const int lt = wid * 16 + t;
    const int n = blockIdx.x * TPB + lt;
    double acc[NEXP];
    #pragma unroll
    for (int e = 0; e < NEXP; e++) acc[e] = 0.0;
    #pragma unroll
    for (int i = 0; i < 8; i++) {
      int dd = lane + i * 64;
      double xv = (double)x[(size_t)n * DIM + dd];
      const float* wr = Wg + (size_t)dd * NEXP;
      #pragma unroll
      for (int e = 0; e < NEXP; e++) acc[e] += xv * (double)wr[e];
    }
    #pragma unroll
    for (int s = 32; s > 0; s >>= 1)
      #pragma unroll
      for (int e = 0; e < NEXP; e++) acc[e] += __shfl_xor(acc[e], s, 64);
    if (lane == 0) {
      int i0 = 0;
      #pragma unroll
      for (int e = 1; e < NEXP; e++) if (acc[e] > acc[i0]) i0 = e;
      int i1 = (i0 == 0) ? 1 : 0;
      #pragma unroll
      for (int e = 0; e < NEXP; e++) { if (e == i0 || e == i1) continue; if (acc[e] > acc[i1]) i1 = e; }
      double e1 = exp(acc[i1] - acc[i0]), ssum = 1.0 + e1;
      le[lt][0] = i0; le[lt][1] = i1;
      ls[lt][0] = atomicAdd(&hist[i0], 1);
      ls[lt][1] = atomicAdd(&hist[i1], 1);
      lg[lt][0] = (float)(1.0 / ssum); lg[lt][1] = (float)(e1 / ssum);
    }
  }
  __syncthreads();
  if (threadIdx.x < NEXP)
    base[threadIdx.x] = atomicAdd(&counts[threadIdx.x], hist[threadIdx.x]);
  __syncthreads();
  if (threadIdx.x < TPB) {
    const int lt = threadIdx.x;
    const int n = blockIdx.x * TPB + lt;
    const int i0 = le[lt][0], i1 = le[lt][1];
    tok_e[n] = make_int2(i0, i1);
    tok_slot[n] = make_int2(base[i0] + ls[lt][0], base[i1] + ls[lt][1]);
    tok_g[n] = make_float2(lg[lt][0], lg[lt][1]);
  }
}

// ---------------- 128-aligned segment offsets + per-M-tile expert id ----------------
__global__ void offsets_kernel(const int* __restrict__ counts, int* __restrict__ offsets,
                               int* __restrict__ mtile_e) {
  if (threadIdx.x == 0 && blockIdx.x == 0) {
    int off = 0;
    for (int e = 0; e < NEXP; e++) { offsets[e] = off; off += (counts[e] + 127) & ~127; }
    offsets[NEXP] = off;
    for (int t = 0; t < NMT; t++) {
      int r = t * 128, e = NEXP - 1;
      for (int q = 0; q < NEXP; q++)
        if (r >= offsets[q] && r < offsets[q + 1]) { e = q; break; }
      mtile_e[t] = e;
    }
  }
}

// ---------------- gather routed token rows into contiguous bf16 segments ----------------
__global__ void gather_kernel(const float* __restrict__ x, const int2* __restrict__ tok_e,
                              const int2* __restrict__ tok_slot, const float2* __restrict__ tok_g,
                              const int* __restrict__ offsets, int* __restrict__ tokrow,
                              float* __restrict__ gaterow, ushort4* __restrict__ xg) {
  const int p = blockIdx.x, n = p >> 1, k = p & 1;
  int2 te = tok_e[n]; int2 ts = tok_slot[n]; float2 tg = tok_g[n];
  const int e = k ? te.y : te.x;
  const int slot = k ? ts.y : ts.x;
  const float g = k ? tg.y : tg.x;
  const int r = offsets[e] + slot;
  if (threadIdx.x == 0) { tokrow[r] = n; gaterow[r] = g; }
  const float4* xr = (const float4*)(x + (size_t)n * DIM);
  float4 v = xr[threadIdx.x];
  ushort4 o;
  o.x = f2bf(v.x); o.y = f2bf(v.y); o.z = f2bf(v.z); o.w = f2bf(v.w);
  xg[(size_t)r * (DIM / 4) + threadIdx.x] = o;
}

// ---------------- 128x128xBK32 bf16 MFMA GEMM core, global_load_lds staging ----------------
template <int K, int LDA, int LDB>
__device__ __forceinline__ void gemm_core(const unsigned short* __restrict__ A,
                                          const unsigned short* __restrict__ B,
                                          int m0, int n0, f32x4 acc[4][4]) {
  __shared__ __align__(16) unsigned short As[128 * 32];
  __shared__ __align__(16) unsigned short Bs[128 * 32];
  const int tid = threadIdx.x;
  const int wid = tid >> 6, lane = tid & 63;
  const int wm = (wid >> 1) * 64, wn = (wid & 1) * 64;
  const int quad = lane >> 4, l16 = lane & 15;
  const int srow = tid >> 2;          // 0..63
  const int scol = (tid & 3) << 3;    // 0,8,16,24 (elements)
  // LDS byte offset of this lane's slot is exactly 16*tid = (1024*wid) + 16*lane,
  // so per-wave base As+512*wid matches the HW's base+lane*16 scatter.
  unsigned short* As_w = As + 512 * wid;
  unsigned short* Bs_w = Bs + 512 * wid;
  const unsigned short* Ar0 = A + (size_t)(m0 + srow) * LDA + scol;
  const unsigned short* Ar1 = A + (size_t)(m0 + srow + 64) * LDA + scol;
  const unsigned short* Br0 = B + (size_t)(n0 + srow) * LDB + scol;
  const unsigned short* Br1 = B + (size_t)(n0 + srow + 64) * LDB + scol;
  #pragma unroll 1
  for (int kt = 0; kt < K; kt += 32) {
    __syncthreads();                      // prior iteration's LDS reads done
    gld16(Ar0 + kt, As_w);
    gld16(Ar1 + kt, As_w + 64 * 32);
    gld16(Br0 + kt, Bs_w);
    gld16(Br1 + kt, Bs_w + 64 * 32);
    __syncthreads();                      // drains vmcnt before ds_read
    bf16x8 af[4], bfr[4];
    #pragma unroll
    for (int i = 0; i < 4; i++) {
      af[i]  = *(const bf16x8*)(As + (wm + i * 16 + l16) * 32 + quad * 8);
      bfr[i] = *(const bf16x8*)(Bs + (wn + i * 16 + l16) * 32 + quad * 8);
    }
    #pragma unroll
    for (int mi = 0; mi < 4; mi++)
      #pragma unroll
      for (int ni = 0; ni < 4; ni++)
        acc[mi][ni] = __builtin_amdgcn_mfma_f32_16x16x32_bf16(af[mi], bfr[ni], acc[mi][ni], 0, 0, 0);
  }
}

// ---------------- GEMM1: h = relu(xg @ W1[e] + b1[e]) -> bf16 ----------------
__global__ __launch_bounds__(256) void gemm1_kernel(const unsigned short* __restrict__ xg,
    const unsigned short* __restrict__ W1t, const int* __restrict__ mtile_e,
    const float* __restrict__ b1, unsigned short* __restrict__ h) {
  const int bm = blockIdx.x, bn = blockIdx.y;
  const int e = mtile_e[bm];
  f32x4 acc[4][4];
  #pragma unroll
  for (int i = 0; i < 4; i++)
    #pragma unroll
    for (int j = 0; j < 4; j++) acc[i][j] = (f32x4){0.f, 0.f, 0.f, 0.f};
  gemm_core<DIM, DIM, DIM>(xg, W1t + (size_t)e * FDIM * DIM, bm * 128, bn * 128, acc);
  const int tid = threadIdx.x, wid = tid >> 6, lane = tid & 63;
  const int wm = (wid >> 1) * 64, wn = (wid & 1) * 64, quad = lane >> 4, l16 = lane & 15;
  #pragma unroll
  for (int mi = 0; mi < 4; mi++) {
    #pragma unroll
    for (int ni = 0; ni < 4; ni++) {
      const int col = bn * 128 + wn + ni * 16 + l16;
      const float bb = b1[e * FDIM + col];
      #pragma unroll
      for (int r = 0; r < 4; r++) {
        const int row = bm * 128 + wm + mi * 16 + quad * 4 + r;
        float v = acc[mi][ni][r] + bb;
        h[(size_t)row * FDIM + col] = f2bf(v > 0.f ? v : 0.f);
      }
    }
  }
}

// ---------------- GEMM2: o = h @ W2[e] + b2[e]; scatter gate*exp(o) ----------------
__global__ __launch_bounds__(256) void gemm2_kernel(const unsigned short* __restrict__ h,
    const unsigned short* __restrict__ W2t, const int* __restrict__ mtile_e,
    const int* __restrict__ tokrow, const float* __restrict__ gaterow,
    const float* __restrict__ b2, float* __restrict__ out) {
  const int bm = blockIdx.x, bn = blockIdx.y;
  const int e = mtile_e[bm];
  f32x4 acc[4][4];
  #pragma unroll
  for (int i = 0; i < 4; i++)
    #pragma unroll
    for (int j = 0; j < 4; j++) acc[i][j] = (f32x4){0.f, 0.f, 0.f, 0.f};
  gemm_core<FDIM, FDIM, FDIM>(h, W2t + (size_t)e * DIM * FDIM, bm * 128, bn * 128, acc);
  const int tid = threadIdx.x, wid = tid >> 6, lane = tid & 63;
  const int wm = (wid >> 1) * 64, wn = (wid & 1) * 64, quad = lane >> 4, l16 = lane & 15;
  #pragma unroll
  for (int mi = 0; mi < 4; mi++) {
    #pragma unroll
    for (int r = 0; r < 4; r++) {
      const int row = bm * 128 + wm + mi * 16 + quad * 4 + r;
      const float g = gaterow[row];
      if (g != 0.f) {
        const int tok = tokrow[row];
        #pragma unroll
        for (int ni = 0; ni < 4; ni++) {
          const int col = bn * 128 + wn + ni * 16 + l16;
          const float o = acc[mi][ni][r] + b2[e * DIM + col];
          atomicAdd(&out[(size_t)tok * DIM + col], g * expf(o));
        }
      }
    }
  }
}

// ---------------- finalize: log with eps floor, in place ----------------
__global__ void log_kernel(float* __restrict__ out) {
  const int i = blockIdx.x * 256 + threadIdx.x;
  float v = out[i];
  v = (v == 0.0f) ? 2.220446049250313e-16f : v;
  out[i] = logf(v);
}

extern "C" void kernel_launch(void* const* d_in, const int* in_sizes, int n_in,
                              void* d_out, int out_size, void* d_ws, size_t ws_size,
                              hipStream_t stream) {
  const float* x  = (const float*)d_in[0];
  const float* Wg = (const float*)d_in[1];
  const float* W1 = (const float*)d_in[2];
  const float* b1 = (const float*)d_in[3];
  const float* W2 = (const float*)d_in[4];
  const float* b2 = (const float*)d_in[5];
  float* out = (float*)d_out;
  char* ws = (char*)d_ws;

  unsigned short* W1t = (unsigned short*)(ws + OFF_W1T);
  unsigned short* W2t = (unsigned short*)(ws + OFF_W2T);
  unsigned short* h   = (unsigned short*)(ws + OFF_H);
  int* meta    = (int*)(ws + OFF_META);
  int* counts  = meta;
  int* offsets = meta + 8;
  int* mtile_e = meta + 32;
  int* tokrow     = (int*)(ws + OFF_TOKROW);
  float* gaterow  = (float*)(ws + OFF_GATEROW);
  unsigned short* xg = (unsigned short*)(ws + OFF_XG);
  int2* tok_e    = (int2*)(ws + OFF_TOKE);
  int2* tok_slot = (int2*)(ws + OFF_TOKSLOT);
  float2* tok_g  = (float2*)(ws + OFF_TOKG);

  hipMemsetAsync(d_out, 0, (size_t)NTOK * DIM * 4, stream);
  hipMemsetAsync(ws + ZERO_START, 0, ZERO_LEN, stream);

  transpose_cast<<<dim3(FDIM / 32, DIM / 32, NEXP), 256, 0, stream>>>(W1, W1t, DIM, FDIM);
  transpose_cast<<<dim3(DIM / 32, FDIM / 32, NEXP), 256, 0, stream>>>(W2, W2t, FDIM, DIM);
  gate_kernel<<<GB, 256, 0, stream>>>(x, Wg, counts, tok_e, tok_slot, tok_g);
  offsets_kernel<<<1, 64, 0, stream>>>(counts, offsets, mtile_e);
  gather_kernel<<<NTOK * 2, 128, 0, stream>>>(x, tok_e, tok_slot, tok_g, offsets,
                                              tokrow, gaterow, (ushort4*)xg);
  gemm1_kernel<<<dim3(NMT, FDIM / 128), 256, 0, stream>>>(xg, W1t, mtile_e, b1, h);
  gemm2_kernel<<<dim3(NMT, DIM / 128), 256, 0, stream>>>(h, W2t, mtile_e, tokrow, gaterow, b2, out);
  log_kernel<<<NTOK * DIM / 256, 256, 0, stream>>>(out);
}